// Round 1
// 521.961 us; speedup vs baseline: 1.0123x; 1.0123x over previous
//
#include <hip/hip_runtime.h>
#include <float.h>

typedef __bf16 bf16x8 __attribute__((ext_vector_type(8)));
typedef float  f32x16 __attribute__((ext_vector_type(16)));

// ws byte layout
#define WS_EE    0                           // 3*1024 floats
#define WS_SLOT  12288                       // 128 float loss slots
#define WS_IMG0  16384                       // emb split images
#define WS_IMG1  (WS_IMG0 + 4096 * 64)
#define WS_IMG2  (WS_IMG1 + 4096 * 128)

__device__ __forceinline__ short f2bf(float f) {
    unsigned u = __float_as_uint(f);
    unsigned r = (u + 0x7FFFu + ((u >> 16) & 1u)) >> 16;
    return (short)r;
}
__device__ __forceinline__ float bf2f(short s) {
    return __uint_as_float(((unsigned)(unsigned short)s) << 16);
}
__device__ __forceinline__ unsigned pk2(short a, short b) {
    return (unsigned)(unsigned short)a | ((unsigned)(unsigned short)b << 16);
}

// ---------------------------------------------------------------------------
// Async 32KB tile stage: 8 x global_load_lds dwordx4 per thread.
// Image layout == LDS layout, so the copy is linear: dst = base + tid*16,
// exactly the wave-uniform-base + lane*16 pattern the DMA requires.
// ---------------------------------------------------------------------------
__device__ __forceinline__ void stage_tile(const char* __restrict__ src, short* dst, int tid)
{
    const char* s = src + tid * 16;
    char* d = (char*)dst + tid * 16;
#pragma unroll
    for (int it = 0; it < 8; ++it) {
        __builtin_amdgcn_global_load_lds(
            (const __attribute__((address_space(1))) void*)(s + it * 4096),
            (__attribute__((address_space(3))) void*)(d + it * 4096),
            16, 0, 0);
    }
}

// ---------------------------------------------------------------------------
// Fused prep: |e|^2 for all codebooks + pre-split hi/lo bf16 images.
// Image per level: [ct 0..7][kc 0..KCS-1] regions of 128 rows x 256 B.
// Granule q stored at physical slot q ^ (r & 15): 16 consecutive rows map a
// fixed granule to 16 DISTINCT slots -> conflict-free b128 reads (the old
// &7 swizzle was a 4-way conflict on every read: slots repeat with period 8
// and slots s/s+8 alias the same banks).
// ---------------------------------------------------------------------------
__global__ void prep_all(const float* __restrict__ e0, const float* __restrict__ e1,
                         const float* __restrict__ e2, char* __restrict__ ws)
{
    int bid = blockIdx.x;
    if (bid >= 224) {
        // ---- |e|^2 ----
        int b2 = bid - 224;
        float* ee = (float*)ws;
        const float* e; float* o; int D;
        if (b2 < 256)      { e = e0; o = ee;        D = 64;  }
        else if (b2 < 512) { e = e1; o = ee + 1024; D = 128; b2 -= 256; }
        else               { e = e2; o = ee + 2048; D = 256; b2 -= 512; }
        int k  = b2 * 4 + (threadIdx.x >> 6);
        int ln = threadIdx.x & 63;
        float s = 0.f;
        for (int d = ln; d < D; d += 64) { float v = e[(size_t)k * D + d]; s = fmaf(v, v, s); }
#pragma unroll
        for (int m = 32; m >= 1; m >>= 1) s += __shfl_xor(s, m);
        if (ln == 0) o[k] = s;
        return;
    }
    // ---- image prep ----
    int flat = bid * 256 + threadIdx.x;              // [0, 57344)
    const float* emb; char* img; int D, id;
    if (flat < 8192)       { emb = e0; img = ws + WS_IMG0; D = 64;  id = flat; }
    else if (flat < 24576) { emb = e1; img = ws + WS_IMG1; D = 128; id = flat - 8192; }
    else                   { emb = e2; img = ws + WS_IMG2; D = 256; id = flat - 24576; }
    int chunks = D >> 3;
    int c  = id / chunks;
    int ch = id - c * chunks;
    int d0 = ch * 8;
    int kc = d0 >> 6;
    int dd = d0 & 63;
    int q  = ((dd >> 4) << 2) + (((dd >> 3) & 1) << 1);
    int r  = c & 127;
    int ct = c >> 7;
    const float* s = emb + (size_t)c * D + d0;
    unsigned hw[4], lw[4];
#pragma unroll
    for (int j = 0; j < 4; ++j) {
        float va = s[2 * j], vb = s[2 * j + 1];
        short ha = f2bf(va), hb = f2bf(vb);
        short la = f2bf(va - bf2f(ha)), lb = f2bf(vb - bf2f(hb));
        hw[j] = pk2(ha, hb);
        lw[j] = pk2(la, lb);
    }
    char* base = img + ((size_t)(ct * (D >> 6) + kc)) * 32768 + r * 256;
    *(uint4*)(base + (((q    ) ^ (r & 15)) << 4)) = make_uint4(hw[0], hw[1], hw[2], hw[3]);
    *(uint4*)(base + (((q + 1) ^ (r & 15)) << 4)) = make_uint4(lw[0], lw[1], lw[2], lw[3]);
}

// ---------------------------------------------------------------------------
// Main fused kernel LDS (file-scope, shared across template instantiations)
//   g_eb0/g_eb1: double-buffered 32KB e tiles (g_eb0 doubles as x-stage
//   scratch in the prologue and fp32 scratch in the re-resolve path)
// Total ~71KB -> 2 blocks/CU.
// ---------------------------------------------------------------------------
__shared__ __align__(16) short g_eb0[16384];
__shared__ __align__(16) short g_eb1[16384];
__shared__ __align__(16) float g_ee[1024];   // |e|^2 for this level
__shared__ float g_m1[128];
__shared__ float g_m2[128];
__shared__ int   g_i1[128];
__shared__ int   g_sidx[128];
__shared__ float g_d1[128];
__shared__ int   g_flag[130];                // [0]=count, then list
__shared__ unsigned long long g_red;
__shared__ float g_part[4];

template<int D, int HW, int PTS>
__device__ void vq_core3(const float* __restrict__ x, const float* __restrict__ emb,
                         const float* __restrict__ eesq, const char* __restrict__ eimg,
                         float* __restrict__ feat, float* __restrict__ slots,
                         float lscale, float margin, int ptblk)
{
    constexpr int KCS  = D / 64;
    constexpr int ROWG = PTS / 32;   // row groups
    constexpr int TPW  = ROWG;       // code sub-tiles per wave (N_rep)
    constexpr int W    = 4 / ROWG;   // code groups per point
    constexpr int NT   = 8 * KCS;    // total (cg,kc) e-tiles
    constexpr bool SA  = (TPW <= 2); // split accumulator (breaks 3-deep MFMA chain)

    const int tid  = threadIdx.x;
    const int L    = tid & 63;
    const int wave = tid >> 6;
    const int col  = L & 31;
    const int half = L >> 5;
    const int rowg = wave % ROWG;
    const int cgrp = wave / ROWG;

    const int pt0 = ptblk * PTS;     // HW % PTS == 0 -> tile within one batch b
    const int b   = pt0 / HW;
    const int hw0 = pt0 % HW;
    const float* xb = x + (size_t)b * D * HW + hw0;

    // ---- prefetch e tile 0 into buf1 (overlaps the whole x-stage) ----
    stage_tile(eimg, g_eb1, tid);

    // ---- stage x once (split bf16 + &15 swizzle) into buf0, accum |x|^2 ----
    short* gx = g_eb0;
    float ssq = 0.f;
#pragma unroll
    for (int it = 0; it < 4; ++it) {
        int flat = it * 256 + tid;           // [0, PTS*D/8)
        int pt   = flat % PTS;
        int dch  = flat / PTS;
        int d0   = dch * 8;
        int kc   = d0 >> 6;
        int dd   = d0 & 63;
        int q    = ((dd >> 4) << 2) + (((dd >> 3) & 1) << 1);
        unsigned hw_[4], lw_[4];
#pragma unroll
        for (int j = 0; j < 4; ++j) {
            float va = xb[(size_t)(d0 + 2 * j)     * HW + pt];
            float vb = xb[(size_t)(d0 + 2 * j + 1) * HW + pt];
            ssq = fmaf(va, va, ssq);
            ssq = fmaf(vb, vb, ssq);
            short ha = f2bf(va), hb = f2bf(vb);
            short la = f2bf(va - bf2f(ha)), lb = f2bf(vb - bf2f(hb));
            hw_[j] = pk2(ha, hb);
            lw_[j] = pk2(la, lb);
        }
        short* row = gx + kc * (PTS * 128) + pt * 128;
        *(uint4*)(row + (((q    ) ^ (pt & 15)) << 3)) = make_uint4(hw_[0], hw_[1], hw_[2], hw_[3]);
        *(uint4*)(row + (((q + 1) ^ (pt & 15)) << 3)) = make_uint4(lw_[0], lw_[1], lw_[2], lw_[3]);
    }
    // |e|^2 into LDS so the main loop has NO vmem ops besides the prefetches
#pragma unroll
    for (int i = 0; i < 4; ++i) g_ee[i * 256 + tid] = eesq[i * 256 + tid];
    if (tid == 0) g_flag[0] = 0;

    asm volatile("s_waitcnt lgkmcnt(0)" ::: "memory");   // my ds_writes done
    __builtin_amdgcn_s_barrier();                        // all x/ee writes visible
    __builtin_amdgcn_sched_barrier(0);

    // ---- A fragments into registers (read once; never re-read per cg) ----
    const int arow = rowg * 32 + col;
    const short* xrow0 = gx + arow * 128;
    bf16x8 afh[KCS][4], afl[KCS][4];
#pragma unroll
    for (int kc = 0; kc < KCS; ++kc) {
        const short* xck = xrow0 + kc * (PTS * 128);
#pragma unroll
        for (int t4 = 0; t4 < 4; ++t4) {
            int qh = t4 * 4 + half * 2;
            afh[kc][t4] = *(const bf16x8*)(xck + (((qh    ) ^ (arow & 15)) << 3));
            afl[kc][t4] = *(const bf16x8*)(xck + (((qh + 1) ^ (arow & 15)) << 3));
        }
    }
    asm volatile("s_waitcnt lgkmcnt(0)" ::: "memory");   // my af reads complete
    __builtin_amdgcn_s_barrier();                        // all reads done -> buf0 free
    __builtin_amdgcn_sched_barrier(0);
    stage_tile(eimg + 32768, g_eb0, tid);                // e tile 1 -> buf0

    float m1[16], m2[16]; int i1[16];
#pragma unroll
    for (int r = 0; r < 16; ++r) { m1[r] = FLT_MAX; m2[r] = FLT_MAX; i1[r] = 0; }

    for (int cg = 0; cg < 8; ++cg) {
        float eecv[TPW];
#pragma unroll
        for (int tt = 0; tt < TPW; ++tt)
            eecv[tt] = g_ee[cg * 128 + (cgrp * TPW + tt) * 32 + col];

        f32x16 acc[TPW];
        f32x16 acc2[SA ? TPW : 1];
#pragma unroll
        for (int tt = 0; tt < TPW; ++tt)
#pragma unroll
            for (int j = 0; j < 16; ++j) acc[tt][j] = 0.f;
        if constexpr (SA) {
#pragma unroll
            for (int tt = 0; tt < TPW; ++tt)
#pragma unroll
                for (int j = 0; j < 16; ++j) acc2[tt][j] = 0.f;
        }

#pragma unroll
        for (int kc = 0; kc < KCS; ++kc) {
            const int t = cg * KCS + kc;
            short* buft = (t & 1) ? g_eb0 : g_eb1;   // buffer holding tile t (and dest of t+2)
            // tile t ready when own 8 DMA loads of it complete; tile t+1's 8 stay in flight
            if (t == NT - 1) asm volatile("s_waitcnt vmcnt(0)" ::: "memory");
            else             asm volatile("s_waitcnt vmcnt(8)" ::: "memory");
            __builtin_amdgcn_s_barrier();            // everyone's DMA for tile t done
            __builtin_amdgcn_sched_barrier(0);
#pragma unroll
            for (int t4 = 0; t4 < 4; ++t4) {
                const int qh = t4 * 4 + half * 2;
#pragma unroll
                for (int tt = 0; tt < TPW; ++tt) {
                    const int brow = (cgrp * TPW + tt) * 32 + col;
                    const short* br = buft + brow * 128;
                    bf16x8 bh = *(const bf16x8*)(br + (((qh    ) ^ (brow & 15)) << 3));
                    bf16x8 bl = *(const bf16x8*)(br + (((qh + 1) ^ (brow & 15)) << 3));
                    if constexpr (SA) {
                        acc [tt] = __builtin_amdgcn_mfma_f32_32x32x16_bf16(afh[kc][t4], bh, acc [tt], 0, 0, 0);
                        acc2[tt] = __builtin_amdgcn_mfma_f32_32x32x16_bf16(afh[kc][t4], bl, acc2[tt], 0, 0, 0);
                        acc2[tt] = __builtin_amdgcn_mfma_f32_32x32x16_bf16(afl[kc][t4], bh, acc2[tt], 0, 0, 0);
                    } else {
                        acc[tt] = __builtin_amdgcn_mfma_f32_32x32x16_bf16(afh[kc][t4], bh, acc[tt], 0, 0, 0);
                        acc[tt] = __builtin_amdgcn_mfma_f32_32x32x16_bf16(afh[kc][t4], bl, acc[tt], 0, 0, 0);
                        acc[tt] = __builtin_amdgcn_mfma_f32_32x32x16_bf16(afl[kc][t4], bh, acc[tt], 0, 0, 0);
                    }
                }
            }
            asm volatile("s_waitcnt lgkmcnt(0)" ::: "memory");  // my b-reads complete
            __builtin_amdgcn_s_barrier();                       // all readers done with buft
            __builtin_amdgcn_sched_barrier(0);
            if (t + 2 < NT) stage_tile(eimg + (size_t)(t + 2) * 32768, buft, tid);
        }

        // ---- fold codes of this group into (m1, i1, m2) ----
#pragma unroll
        for (int tt = 0; tt < TPW; ++tt) {
            int c = cg * 128 + (cgrp * TPW + tt) * 32 + col;
            float eec = eecv[tt];
#pragma unroll
            for (int r = 0; r < 16; ++r) {
                float av = acc[tt][r];
                if constexpr (SA) av += acc2[tt][r];
                float dist = fmaf(-2.f, av, eec);
                m2[r] = __builtin_amdgcn_fmed3f(dist, m1[r], m2[r]);
                bool lt = dist < m1[r];
                m1[r] = lt ? dist : m1[r];
                i1[r] = lt ? c : i1[r];
            }
        }
    }

    // ---- butterfly across the 32 lanes of each half ----
#pragma unroll
    for (int r = 0; r < 16; ++r) {
#pragma unroll
        for (int msk = 1; msk <= 16; msk <<= 1) {
            float om1 = __shfl_xor(m1[r], msk);
            int   oi  = __shfl_xor(i1[r], msk);
            float om2 = __shfl_xor(m2[r], msk);
            float mx  = fmaxf(m1[r], om1);
            m2[r] = fminf(mx, fminf(m2[r], om2));
            bool tk = (om1 < m1[r]) || (om1 == m1[r] && oi < i1[r]);
            m1[r] = tk ? om1 : m1[r];
            i1[r] = tk ? oi  : i1[r];
        }
    }
    // ---- publish per (point, code-group) ----
#pragma unroll
    for (int r = 0; r < 16; ++r) {
        int r16 = (r & 3) + 8 * (r >> 2) + 4 * half;
        if (col == r16) {
            int p = rowg * 32 + r16;
            g_m1[p * W + cgrp] = m1[r];
            g_m2[p * W + cgrp] = m2[r];
            g_i1[p * W + cgrp] = i1[r];
        }
    }
    __syncthreads();

    // ---- merge code groups, margin-certify ----
    if (tid < PTS) {
        float bm1 = FLT_MAX, bm2 = FLT_MAX; int bi = 0x7FFFFFFF;
#pragma unroll
        for (int s = 0; s < W; ++s) {
            float am1 = g_m1[tid * W + s];
            float am2 = g_m2[tid * W + s];
            int   ai  = g_i1[tid * W + s];
            float mx  = fmaxf(bm1, am1);
            bm2 = fminf(mx, fminf(bm2, am2));
            bool tk = (am1 < bm1) || (am1 == bm1 && ai < bi);
            bm1 = tk ? am1 : bm1;
            bi  = tk ? ai  : bi;
        }
        g_sidx[tid] = bi;
        g_d1[tid]   = bm1;
        if (bm2 - bm1 <= margin) {
            int pos = atomicAdd(&g_flag[0], 1);
            g_flag[1 + pos] = tid;
        }
    }
    __syncthreads();

    // ---- rare exact fp32 re-resolve for near-ties ----
    int nf = g_flag[0];
    float* sx = (float*)g_eb0;   // e buffers no longer needed
    for (int i = 0; i < nf; ++i) {
        int p   = g_flag[1 + i];
        int phw = hw0 + p;
        for (int d = tid; d < D; d += 256) sx[d] = x[((size_t)b * D + d) * HW + phw];
        if (tid == 0) g_red = ~0ull;
        __syncthreads();
#pragma unroll
        for (int j = 0; j < 4; ++j) {
            int c = j * 256 + tid;
            float s = 0.f;
#pragma unroll 4
            for (int d = 0; d < D; ++d) s = fmaf(sx[d], emb[(size_t)c * D + d], s);
            float dist = fmaf(-2.f, s, g_ee[c]);
            unsigned u = __float_as_uint(dist);
            u = (u >> 31) ? ~u : (u | 0x80000000u);
            unsigned long long pkv = ((unsigned long long)u << 32) | (unsigned)c;
            atomicMin(&g_red, pkv);
        }
        __syncthreads();
        if (tid == 0) {
            unsigned u = (unsigned)(g_red >> 32);
            unsigned orig = (u & 0x80000000u) ? (u ^ 0x80000000u) : ~u;
            g_sidx[p] = (int)(g_red & 0xFFFFFFFFu);
            g_d1[p]   = __uint_as_float(orig);
        }
        __syncthreads();
    }

    // ---- epilogue: gather chosen codes, write NCHW features ----
#pragma unroll 4
    for (int it = 0; it < (PTS * D) / 256; ++it) {
        int flat = it * 256 + tid;
        int p  = flat % PTS;
        int dd = flat / PTS;
        int k  = g_sidx[p];
        feat[((size_t)b * D + dd) * HW + hw0 + p] = emb[(size_t)k * D + dd];
    }

    // ---- loss: sum(dist_chosen) + sum(|x|^2), one atomic into spread slots ----
    float lsum = ssq;
    if (tid < PTS) lsum += g_d1[tid];
#pragma unroll
    for (int m = 32; m >= 1; m >>= 1) lsum += __shfl_xor(lsum, m);
    if (L == 0) g_part[wave] = lsum;
    __syncthreads();
    if (tid == 0) {
        float tot = (g_part[0] + g_part[1]) + (g_part[2] + g_part[3]);
        atomicAdd(&slots[blockIdx.x & 127], tot * lscale);
    }
}

__global__ __launch_bounds__(256, 2)
void vq_main3(const float* __restrict__ x0, const float* __restrict__ e0,
              const float* __restrict__ x1, const float* __restrict__ e1,
              const float* __restrict__ x2, const float* __restrict__ e2,
              char* __restrict__ ws,
              float* __restrict__ f0, float* __restrict__ f1, float* __restrict__ f2)
{
    const float* ee = (const float*)ws;
    float* slots = (float*)(ws + WS_SLOT);
    int bid = blockIdx.x;
    if (bid < 480) {
        vq_core3<256, 1920, 32>(x2, e2, ee + 2048, ws + WS_IMG2, f2, slots,
                                0.25f / 3932160.f, 8e-3f, bid);
    } else if (bid < 1440) {
        vq_core3<128, 7680, 64>(x1, e1, ee + 1024, ws + WS_IMG1, f1, slots,
                                0.25f / 7864320.f, 5e-3f, bid - 480);
    } else {
        vq_core3<64, 30720, 128>(x0, e0, ee, ws + WS_IMG0, f0, slots,
                                 0.25f / 15728640.f, 4e-3f, bid - 1440);
    }
}

// ---------------------------------------------------------------------------
__global__ void loss_finish(const float* __restrict__ slots, float* __restrict__ out)
{
    int t = threadIdx.x;     // 128
    float v = slots[t];
#pragma unroll
    for (int m = 32; m >= 1; m >>= 1) v += __shfl_xor(v, m);
    __shared__ float p2[2];
    if ((t & 63) == 0) p2[t >> 6] = v;
    __syncthreads();
    if (t == 0) out[0] = p2[0] + p2[1];
}

// ---------------------------------------------------------------------------
extern "C" void kernel_launch(void* const* d_in, const int* in_sizes, int n_in,
                              void* d_out, int out_size, void* d_ws, size_t ws_size,
                              hipStream_t stream)
{
    const float* x0 = (const float*)d_in[0];
    const float* e0 = (const float*)d_in[1];
    const float* x1 = (const float*)d_in[2];
    const float* e1 = (const float*)d_in[3];
    const float* x2 = (const float*)d_in[4];
    const float* e2 = (const float*)d_in[5];

    float* out  = (float*)d_out;
    float* f0   = out + 1;
    float* f1   = f0 + 15728640;   // 8*64*96*320
    float* f2   = f1 + 7864320;    // 8*128*48*160

    char* ws = (char*)d_ws;
    float* slots = (float*)(ws + WS_SLOT);

    hipMemsetAsync(slots, 0, 128 * sizeof(float), stream);

    prep_all<<<992, 256, 0, stream>>>(e0, e1, e2, ws);

    vq_main3<<<3360, 256, 0, stream>>>(x0, e0, x1, e1, x2, e2, ws, f0, f1, f2);

    loss_finish<<<1, 128, 0, stream>>>(slots, out);
}